// Round 2
// baseline (148.880 us; speedup 1.0000x reference)
//
#include <hip/hip_runtime.h>
#include <hip/hip_bf16.h>

// Problem constants (B,T,C,H from reference)
#define BATCH 8
#define SEQ   2048
#define EMB   1024
#define HD    128

typedef __attribute__((ext_vector_type(8))) short bf16x8;  // MFMA A/B frag (4 VGPR)
typedef __attribute__((ext_vector_type(4))) float f32x4;   // MFMA C/D frag

__device__ __forceinline__ short f2bf(float f) {           // RNE
    union { float f; unsigned u; } v; v.f = f;
    unsigned r = v.u + 0x7fffu + ((v.u >> 16) & 1u);
    return (short)(r >> 16);
}

// async global->LDS 16B/lane copy (wave-uniform LDS base + lane*16, per-lane src)
__device__ __forceinline__ void glds16(const short* g, short* l) {
    __builtin_amdgcn_global_load_lds(
        (const __attribute__((address_space(1))) unsigned int*)g,
        (__attribute__((address_space(3))) unsigned int*)l, 16, 0, 0);
}

// ===========================================================================
// FRAGMENT-IMAGE LAYOUTS (R6-verified): every MFMA fragment = one contiguous
// 1KB region = one fully-coalesced 16B/lane load for the consuming wave.
// W image (nh 0=K,1=V; k-chunk kc): slot(kk,f,l,q) -> W[nh*128+f*16+l][kc*64+kk*32+q*8+e]
// K image (b, jt): slot(kc,js,l,q) -> K[js*16+l][kc*32+q*8+e]
// V image (b, jt): slot(jc,f,l,q)  -> V[jc*32+q*8+e][f*16+l]
// ===========================================================================

__global__ void prep_w(const float* __restrict__ Wk, const float* __restrict__ Wv,
                       short* __restrict__ Wimg) {
    int g  = blockIdx.x * 256 + threadIdx.x;   // 0..32767
    int q  = g & 3;
    int l  = (g >> 2) & 15;
    int f  = (g >> 6) & 7;
    int kk = (g >> 9) & 1;
    int kc = (g >> 10) & 15;
    int nh = (g >> 14) & 1;
    const float* src = (nh ? Wv : Wk) + (size_t)(f * 16 + l) * EMB + kc * 64 + kk * 32 + q * 8;
    float4 f0 = *(const float4*)src;
    float4 f1 = *(const float4*)(src + 4);
    bf16x8 v;
    v[0]=f2bf(f0.x); v[1]=f2bf(f0.y); v[2]=f2bf(f0.z); v[3]=f2bf(f0.w);
    v[4]=f2bf(f1.x); v[5]=f2bf(f1.y); v[6]=f2bf(f1.z); v[7]=f2bf(f1.w);
    *(bf16x8*)&Wimg[(size_t)g * 8] = v;
}

// ---------------------------------------------------------------------------
// proj_kernel v9 (R11): [K|V] = x @ [Wk|Wv]^T, latency-hiding restructure.
//
// THEORY: v8 (grid 256 x 512thr) was 1 block/CU: all 8 waves share one
// barrier, x-prefetch depth 1 iter (~400cy) vs ~900cy HBM latency -> ~500cy
// dead stall at every stage point, nothing co-resident to fill it. HBM floor
// for the 67MB x read is 10.6us; v8 measured ~30us.
//
// v9: M=32-row blocks, grid 512 x 256thr -> 2 INDEPENDENT blocks/CU (TLP
// fills barrier stalls); x pipelined 2 chunks ahead (regs, ~800cy cover);
// W-frags prefetched 1 kc ahead (regs, covers ~300cy L2 latency). 4 waves:
// wave = (nh = w>>1, fquad = w&1 -> f in {fq*4..fq*4+3}); acc[2 mf][4 f].
// LDS 16KB union, VGPR ~150 -> 2 blocks/CU resident. Kimg/Vimg output
// byte-identical to v8 (half-tile epilogue remap element-checked).
// W L2 traffic doubles vs M=64 (268MB, ~8us aggregate) but stays under the
// HBM floor -> still HBM/latency-bound. attn consumes images unchanged.
// ---------------------------------------------------------------------------
__global__ __launch_bounds__(256, 2)
void proj_kernel(const float* __restrict__ x, const short* __restrict__ Wimg,
                 short* __restrict__ Kimg,    // [8][32] 16KB images
                 short* __restrict__ Vimg)    // [8][32] 16KB images
{
    __shared__ __align__(16) union {
        short A[2][32][72];          // 9.2 KB A staging dbuf (+8 pad rows)
        short ep[8192];              // 16 KB epilogue: [K half | V half]
    } sm;

    const int tid  = threadIdx.x;
    const int wave = tid >> 6;
    const int lane = tid & 63;
    const int quad = lane >> 4;
    const int l16  = lane & 15;
    const int nh   = wave >> 1;        // 0 = K half, 1 = V half
    const int fb   = (wave & 1) * 4;   // f-quad base within the half
    const int mt   = blockIdx.x;       // 0..511 (32-row tile)
    const int half = mt & 1;           // which half of the 64-row image tile
    const int t64  = mt >> 1;          // 64-row image tile index 0..255
    const int row0 = mt * 32;

    const int srow = tid >> 3, sseg = tid & 7;
    const float* xsrc = x + (size_t)(row0 + srow) * EMB + sseg * 8;
    const short* wsrc = Wimg + (size_t)nh * 131072;

    f32x4 acc[2][4];                   // [mf][fi]
#pragma unroll
    for (int a = 0; a < 2; ++a)
#pragma unroll
        for (int c = 0; c < 4; ++c) acc[a][c] = f32x4{0.f, 0.f, 0.f, 0.f};

    // ---- prime: chunk0 -> LDS[0]; chunk1 -> regs; W(kc=0) -> regs ----
    float4 p0, p1;                     // x chunk kc+1 (staged at end of iter kc)
    bf16x8 bw[2][4];                   // W frags for current kc
    {
        float4 a0 = *(const float4*)xsrc;
        float4 a1 = *(const float4*)(xsrc + 4);
        bf16x8 v;
        v[0]=f2bf(a0.x); v[1]=f2bf(a0.y); v[2]=f2bf(a0.z); v[3]=f2bf(a0.w);
        v[4]=f2bf(a1.x); v[5]=f2bf(a1.y); v[6]=f2bf(a1.z); v[7]=f2bf(a1.w);
        *(bf16x8*)&sm.A[0][srow][sseg * 8] = v;
        p0 = *(const float4*)(xsrc + 64);
        p1 = *(const float4*)(xsrc + 68);
#pragma unroll
        for (int kk = 0; kk < 2; ++kk)
#pragma unroll
            for (int fi = 0; fi < 4; ++fi)
                bw[kk][fi] = *(const bf16x8*)&wsrc[(((kk * 8 + fb + fi) * 16 + l16) * 4 + quad) * 8];
    }
    __syncthreads();

#pragma unroll 2
    for (int kc = 0; kc < 16; ++kc) {
        const int cur = kc & 1;
        float4 n0, n1;
        if (kc < 14) {                 // x chunk kc+2: 2-deep HBM pipeline
            const float* nx = xsrc + (kc + 2) * 64;
            n0 = *(const float4*)nx;
            n1 = *(const float4*)(nx + 4);
        }
        bf16x8 nw[2][4];
        if (kc < 15) {                 // W frags kc+1: 1-deep L2 pipeline
            const short* wc = wsrc + (size_t)(kc + 1) * 8192;
#pragma unroll
            for (int kk = 0; kk < 2; ++kk)
#pragma unroll
                for (int fi = 0; fi < 4; ++fi)
                    nw[kk][fi] = *(const bf16x8*)&wc[(((kk * 8 + fb + fi) * 16 + l16) * 4 + quad) * 8];
        }

#pragma unroll
        for (int kk = 0; kk < 2; ++kk)
#pragma unroll
            for (int mf = 0; mf < 2; ++mf) {
                bf16x8 af = *(const bf16x8*)&sm.A[cur][mf * 16 + l16][kk * 32 + quad * 8];
#pragma unroll
                for (int fi = 0; fi < 4; ++fi)
                    acc[mf][fi] = __builtin_amdgcn_mfma_f32_16x16x32_bf16(af, bw[kk][fi], acc[mf][fi], 0, 0, 0);
            }

        if (kc < 15) {                 // stage chunk kc+1 (loaded 2 iters ago)
            bf16x8 v;
            v[0]=f2bf(p0.x); v[1]=f2bf(p0.y); v[2]=f2bf(p0.z); v[3]=f2bf(p0.w);
            v[4]=f2bf(p1.x); v[5]=f2bf(p1.y); v[6]=f2bf(p1.z); v[7]=f2bf(p1.w);
            *(bf16x8*)&sm.A[cur ^ 1][srow][sseg * 8] = v;
        }
        if (kc < 14) { p0 = n0; p1 = n1; }
        if (kc < 15) {
#pragma unroll
            for (int kk = 0; kk < 2; ++kk)
#pragma unroll
                for (int fi = 0; fi < 4; ++fi) bw[kk][fi] = nw[kk][fi];
        }
        __syncthreads();
    }

    // ---- epilogue: scatter C into half-tile fragment images in LDS ----
    // K half local: (((h>>5)*2 + mf)*16 + qr)*4 + ((h>>3)&3))*8 + (h&7)
    // V half local: 4096 + ((h>>4)*16 + (h&15))*4 + ((r>>3)&3))*8 + (r&7)
#pragma unroll
    for (int mf = 0; mf < 2; ++mf)
#pragma unroll
        for (int fi = 0; fi < 4; ++fi)
#pragma unroll
            for (int r = 0; r < 4; ++r) {
                const int rl = mf * 16 + quad * 4 + r;           // row within 32
                const int h  = (fb + fi) * 16 + l16;             // col within half
                int idx;
                if (nh == 0)
                    idx = ((((h >> 5) * 2 + ((rl >> 4) & 1)) * 16 + (rl & 15)) * 4 + ((h >> 3) & 3)) * 8 + (h & 7);
                else
                    idx = 4096 + (((h >> 4) * 16 + (h & 15)) * 4 + ((rl >> 3) & 3)) * 8 + (rl & 7);
                sm.ep[idx] = f2bf(acc[mf][fi][r]);
            }
    __syncthreads();

    {   // copy out 16KB in 16B units; K half is 8x1KB strided, V half contiguous
#pragma unroll
        for (int i = 0; i < 4; ++i) {
            const int g = i * 256 + tid;       // 16B unit 0..1023
            short* dst;
            const short* src;
            if (g < 512) {
                const int u = g;               // (kc, js', l, q) packed
                const int gofs = ((((u >> 7) * 4 + half * 2 + ((u >> 6) & 1)) * 16
                                   + ((u >> 2) & 15)) * 4 + (u & 3)) * 8;
                dst = Kimg + (size_t)t64 * 8192 + gofs;
                src = &sm.ep[u * 8];
            } else {
                const int u = g - 512;
                dst = Vimg + (size_t)t64 * 8192 + half * 4096 + u * 8;
                src = &sm.ep[4096 + u * 8];
            }
            *(bf16x8*)dst = *(const bf16x8*)src;
        }
    }
}

// ---------------------------------------------------------------------------
// attn_kernel v8 VERBATIM (R10-verified): LDS-shared K/V flash attention,
// q == k. Block = q-tile pair (2G,2G+1), identical tile count n=(G>>1)+1.
// K dbuf prefetched 1 tile ahead (glds + counted vmcnt + raw s_barrier);
// V staged under the S/softmax phase. No O merge (disjoint h halves).
// ---------------------------------------------------------------------------
#define LOG2E 1.4426950408889634f

__global__ __launch_bounds__(256, 2)
void attn_kernel(const short* __restrict__ Kimg,  // [8][32] images
                 const short* __restrict__ Vimg,  // [8][32] images
                 float* __restrict__ out)         // [B, T, H] fp32
{
    __shared__ __align__(16) short kbuf[2][8192]; // 32 KB K tile dbuf
    __shared__ __align__(16) short vbuf[8192];    // 16 KB V tile
    __shared__ __align__(16) short ps[2][1024];   // per-q-tile swizzled P (16x64)
    __shared__ float lsum[4][16];                 // per-wave l partials

    const int tid  = threadIdx.x;
    const int wave = tid >> 6;
    const int lane = tid & 63;
    const int quad = lane >> 4;
    const int l16  = lane & 15;

    const int b    = blockIdx.x & 7;              // XCD-affinity
    const int gg   = blockIdx.x >> 3;             // 0..63
    const int G    = (blockIdx.x < 256) ? (63 - gg) : (gg - 32); // heavy first
    const int qsel = wave >> 1;                   // which q-tile of the pair
    const int p    = wave & 1;                    // js-half (S) / h-half (PV)
    const int qt   = 2 * G + qsel;
    const int n    = (G >> 1) + 1;                // identical for both q-tiles

    const short* Kb = Kimg + (size_t)b * 32 * 8192;
    const short* Vb = Vimg + (size_t)b * 32 * 8192;

    // Q fragments from the diagonal K-image (Q = K projection)
    bf16x8 qf[4];
    {
        const short* qi = Kb + (size_t)(qt >> 2) * 8192;
        const int jsq = qt & 3;
#pragma unroll
        for (int kc = 0; kc < 4; ++kc)
            qf[kc] = *(const bf16x8*)&qi[(((kc * 4 + jsq) * 16 + l16) * 4 + quad) * 8];
    }

    f32x4 O[4];                                   // h-half: 16q x 64h
#pragma unroll
    for (int f = 0; f < 4; ++f) O[f] = f32x4{0.f, 0.f, 0.f, 0.f};
    float lp[4] = {0.f, 0.f, 0.f, 0.f};

    const float coef = LOG2E * 0.03125f;          // log2(e)/sqrt(C), sqrt(1024)=32
    short* psq = ps[qsel];

    {   // prologue: stage K tile 0 (wave w copies 4KB: 4 x 1KB glds)
        const short* sk = Kb + wave * 2048 + lane * 8;
#pragma unroll
        for (int i = 0; i < 4; ++i)
            glds16(sk + i * 512, &kbuf[0][wave * 2048 + i * 512]);
    }

    int cur = 0;
    for (int jt = 0; jt < n; ++jt) {
        // K[jt] (my 4 glds) done; barrier => all segments visible AND all
        // waves finished reading vbuf/ps/kbuf[cur^1] from the previous step.
        asm volatile("s_waitcnt vmcnt(0)" ::: "memory");
        __builtin_amdgcn_s_barrier();

        {   // stage V[jt] (needed at PV this step -- oldest in flight)
            const short* sv = Vb + (size_t)jt * 8192 + wave * 2048 + lane * 8;
#pragma unroll
            for (int i = 0; i < 4; ++i)
                glds16(sv + i * 512, &vbuf[wave * 2048 + i * 512]);
        }
        const bool more = (jt + 1 < n);
        if (more) {   // prefetch K[jt+1] (drained at next step's loop top)
            const short* sk = Kb + (size_t)(jt + 1) * 8192 + wave * 2048 + lane * 8;
#pragma unroll
            for (int i = 0; i < 4; ++i)
                glds16(sk + i * 512, &kbuf[cur ^ 1][wave * 2048 + i * 512]);
        }

        // ---- S = Q K^T for this wave's js-half (from LDS, layout == image) ----
        const short* kt = kbuf[cur];
        f32x4 S[2];
        S[0] = f32x4{0.f, 0.f, 0.f, 0.f};
        S[1] = f32x4{0.f, 0.f, 0.f, 0.f};
#pragma unroll
        for (int kc = 0; kc < 4; ++kc)
#pragma unroll
            for (int j2 = 0; j2 < 2; ++j2) {
                bf16x8 kf = *(const bf16x8*)&kt[((kc * 4 + p * 2 + j2) * 64 + l16 * 4 + quad) * 8];
                S[j2] = __builtin_amdgcn_mfma_f32_16x16x32_bf16(qf[kc], kf, S[j2], 0, 0, 0);
            }

        // ---- P = exp2(S*coef), causal mask on diag tile; swizzled ps write ----
        const bool diag = (jt == n - 1);
#pragma unroll
        for (int j2 = 0; j2 < 2; ++j2) {
            const int js = p * 2 + j2;
            const int jj = jt * 64 + js * 16 + l16;
            const int cb = js * 2 + (l16 >> 3);
            const int e  = l16 & 7;
#pragma unroll
            for (int r = 0; r < 4; ++r) {
                float vv = S[j2][r] * coef;
                if (diag && (jj > qt * 16 + quad * 4 + r)) vv = -INFINITY;
                float pe = exp2f(vv);             // exp2(-inf) = 0
                lp[r] += pe;
                const int i8 = quad * 4 + r;
                psq[(i8 * 8 + (cb ^ (i8 & 7))) * 8 + e] = f2bf(pe);
            }
        }

        // V[jt] landed (oldest 4), K[jt+1] stays in flight; ps writes visible.
        if (more) asm volatile("s_waitcnt vmcnt(4) lgkmcnt(0)" ::: "memory");
        else      asm volatile("s_waitcnt vmcnt(0) lgkmcnt(0)" ::: "memory");
        __builtin_amdgcn_s_barrier();

        // ---- O += P V for this wave's h-half (full P from shared ps) ----
#pragma unroll
        for (int jc = 0; jc < 2; ++jc) {
            const int pblk = l16 * 8 + ((jc * 4 + quad) ^ (l16 & 7));
            bf16x8 pa = *(const bf16x8*)&psq[pblk * 8];
#pragma unroll
            for (int fo = 0; fo < 4; ++fo) {
                bf16x8 vf = *(const bf16x8*)&vbuf[((jc * 8 + p * 4 + fo) * 64 + l16 * 4 + quad) * 8];
                O[fo] = __builtin_amdgcn_mfma_f32_16x16x32_bf16(pa, vf, O[fo], 0, 0, 0);
            }
        }
        cur ^= 1;
    }

    // ---- l: reduce this wave's js-half partials across the row's 16 lanes ----
#pragma unroll
    for (int r = 0; r < 4; ++r) {
        float s = lp[r];
        s += __shfl_xor(s, 1);
        s += __shfl_xor(s, 2);
        s += __shfl_xor(s, 4);
        s += __shfl_xor(s, 8);
        lp[r] = s;
    }
    if (l16 == 0) {
#pragma unroll
        for (int r = 0; r < 4; ++r) lsum[wave][quad * 4 + r] = lp[r];
    }
    __syncthreads();

    // ---- store: each wave owns a disjoint (q-tile, h-half); no O merge ----
#pragma unroll
    for (int r = 0; r < 4; ++r) {
        const int row16 = quad * 4 + r;
        const float L   = lsum[qsel * 2][row16] + lsum[qsel * 2 + 1][row16];
        const float inv = 1.f / L;
        const int row   = qt * 16 + row16;
        float* dst = out + (size_t)(b * SEQ + row) * HD + p * 64 + l16;
#pragma unroll
        for (int fo = 0; fo < 4; ++fo)
            dst[fo * 16] = O[fo][r] * inv;
    }
}

extern "C" void kernel_launch(void* const* d_in, const int* in_sizes, int n_in,
                              void* d_out, int out_size, void* d_ws, size_t ws_size,
                              hipStream_t stream) {
    const float* x  = (const float*)d_in[0];
    const float* Wk = (const float*)d_in[1];
    // d_in[2] = Wq is UNUSED: reference uses the key projection for q (source bug)
    const float* Wv = (const float*)d_in[3];
    float* out = (float*)d_out;

    short* Wimg = (short*)d_ws;                          // 512 KB
    short* Kimg = Wimg + (size_t)262144;                 // 4 MB
    short* Vimg = Kimg + (size_t)BATCH * 32 * 8192;      // 4 MB

    prep_w<<<128, 256, 0, stream>>>(Wk, Wv, Wimg);
    proj_kernel<<<512, 256, 0, stream>>>(x, Wimg, Kimg, Vimg);
    attn_kernel<<<512, 256, 0, stream>>>(Kimg, Vimg, out);
}